// Round 1
// 466.012 us; speedup vs baseline: 1.1161x; 1.1161x over previous
//
#include <hip/hip_runtime.h>
#include <hip/hip_bf16.h>

typedef unsigned int u32;
typedef unsigned short u16;
typedef unsigned long long u64;
typedef __bf16 bf16x8 __attribute__((ext_vector_type(8)));
typedef short short8 __attribute__((ext_vector_type(8)));
typedef float floatx4 __attribute__((ext_vector_type(4)));

__device__ inline float b2f(u16 b) { return __uint_as_float((u32)b << 16); }
__device__ inline float lo2f(u32 p) { return __uint_as_float(p << 16); }
__device__ inline float hi2f(u32 p) { return __uint_as_float(p & 0xffff0000u); }
__device__ inline u16 f2bs(float f) {   // RNE f32 -> bf16 bits
    __hip_bfloat16 h = __float2bfloat16(f);
    return *reinterpret_cast<u16*>(&h);
}
// element i of an external float array: f32 (fl=1) or packed bf16 (fl=0)
__device__ inline float ldext(const void* p, int fl, int i) {
    return fl ? ((const float*)p)[i] : b2f(((const u16*)p)[i]);
}

// ---------------------------------------------------------------------------
// flags[0]: edge stride (1 = int64 layout, 0 = int32)
// flags[1]: float inputs are f32 (1) or packed bf16 (0)
// flags[2]: E (edges per timestep), decided by probing data extent
__global__ __launch_bounds__(64) void detect_kernel(const int* __restrict__ eb,
                                                    const u32* __restrict__ xw,
                                                    int* __restrict__ flags,
                                                    int S, int n) {
    __shared__ int sh[64 * 3];
    int lane = threadIdx.x & 63;
    int zc = 0, explo = 0;
#pragma unroll
    for (int r = 0; r < 4; ++r) {
        int i = 64 * r + lane;
        zc += (eb[2 * i + 1] == 0) ? 1 : 0;   // int64: odd dwords are hi-words = 0
        u32 w = xw[i];
        int e = (int)((w >> 7) & 0xFF);       // exponent field of LOW half as bf16
        explo += (e >= 96 && e <= 140) ? 1 : 0;
    }
    sh[lane] = zc;
    sh[64 + lane] = explo;
    __syncthreads();
    int fl = 0;
    {
        int z = 0;
        for (int j = 0; j < 64; ++j) z += sh[j];
        fl = (z > 200) ? 1 : 0;   // wave-uniform
    }
    // probe logical indices [S/2, S/2+256): valid node ids => S counts logical
    // elements (E = S/4); garbage => S counts int32 words (E = S/8).
    int vc = 0;
#pragma unroll
    for (int r = 0; r < 4; ++r) {
        int li = S / 2 + 64 * r + lane;
        int v = fl ? eb[2 * li] : eb[li];
        vc += ((unsigned)v < (unsigned)n) ? 1 : 0;
    }
    sh[128 + lane] = vc;
    __syncthreads();
    if (lane == 0) {
        int vtot = 0, etot = 0;
        for (int j = 0; j < 64; ++j) vtot += sh[128 + j];
        for (int j = 0; j < 64; ++j) etot += sh[64 + j];
        flags[0] = fl;
        flags[1] = (etot >= 192) ? 0 : 1;   // bf16-packed signature else f32
        flags[2] = (vtot >= 240) ? (S / 4) : (S / 8);
    }
}

__device__ inline int load_edge(const int* eb, int fl, int idx) {
    return eb[fl ? (idx << 1) : idx];
}

// ---------------------------------------------------------------------------
__global__ __launch_bounds__(256) void deg_kernel(const int* __restrict__ eb,
                                                  const int* __restrict__ flags,
                                                  int t, int* __restrict__ deg, int n) {
    int E = flags[2];
    int e = blockIdx.x * 256 + threadIdx.x;
    if (e < E) {
        int base = t * 2 * E;
        unsigned d = (unsigned)load_edge(eb, flags[0], base + E + e);
        if (d < (unsigned)n) atomicAdd(&deg[d], 1);
    }
}

// ---------------------------------------------------------------------------
// 3-phase exclusive scan of deg -> off, plus bucket-cursor init and dinv
__global__ __launch_bounds__(256) void scan_a(const int* __restrict__ deg,
                                              int* __restrict__ off,
                                              int* __restrict__ btot, int n) {
    __shared__ int tmp[256];
    int t = threadIdx.x;
    int i = blockIdx.x * 256 + t;
    int d = (i < n) ? deg[i] : 0;
    int val = d;
    tmp[t] = val;
    __syncthreads();
    for (int o = 1; o < 256; o <<= 1) {
        int add = (t >= o) ? tmp[t - o] : 0;
        __syncthreads();
        val += add;
        tmp[t] = val;
        __syncthreads();
    }
    if (i < n) off[i] = val - d;
    if (t == 255) btot[blockIdx.x] = val;
}

__global__ __launch_bounds__(256) void scan_b(int* __restrict__ btot, int nb) {
    __shared__ int tmp[256];
    int t = threadIdx.x;
    int d = (t < nb) ? btot[t] : 0;
    int val = d;
    tmp[t] = val;
    __syncthreads();
    for (int o = 1; o < 256; o <<= 1) {
        int add = (t >= o) ? tmp[t - o] : 0;
        __syncthreads();
        val += add;
        tmp[t] = val;
        __syncthreads();
    }
    if (t < nb) btot[t] = val - d;
}

__global__ __launch_bounds__(256) void scan_c(const int* __restrict__ deg,
                                              const int* __restrict__ btot,
                                              int* __restrict__ off,
                                              int* __restrict__ bkcur,
                                              float* __restrict__ dinv,
                                              int n, int shift) {
    int i = blockIdx.x * 256 + threadIdx.x;
    if (i < n) {
        int o = off[i] + btot[blockIdx.x];
        off[i] = o;
        if ((i & ((1 << shift) - 1)) == 0) bkcur[i >> shift] = o;  // bucket start
        if (i == n - 1) off[n] = o + deg[i];                      // total valid edges
        dinv[i] = rsqrtf((float)(deg[i] + 1));  // +1 = self-loop
    }
}

// ---------------------------------------------------------------------------
// CSR fill, pass 1: partition edges into dst-range buckets. Each block handles
// PCHUNK edges, counts per-bucket occupancy in LDS, reserves a contiguous run
// per bucket with ONE global atomicAdd, then writes (dst,src) u64 pairs in
// ~21-pair (~170 B) contiguous runs -> near-full cache lines instead of the
// old 4 B-per-64 B-line scatter (52 MB -> ~9 MB HBM writes).
// Bucket regions mirror the CSR layout exactly: bkcur[b] starts at off[b<<shift].
#define PCHUNK 4096
__global__ __launch_bounds__(256) void part_kernel(const int* __restrict__ eb,
                                                   const int* __restrict__ flags,
                                                   int t, int* __restrict__ bkcur,
                                                   u64* __restrict__ pairs,
                                                   int n, int shift) {
    __shared__ int cnt[256];
    __shared__ int gbase[256];
    const int E = flags[2];
    const int fl = flags[0];
    const int nbuk = (n + (1 << shift) - 1) >> shift;
    const int tid = threadIdx.x;
    for (int i = tid; i < nbuk; i += 256) cnt[i] = 0;
    __syncthreads();
    const int base = t * 2 * E;
    const int e0 = blockIdx.x * PCHUNK;
    int sv[16], dv[16], rk[16];
#pragma unroll
    for (int j = 0; j < 16; ++j) {
        int e = e0 + j * 256 + tid;
        int s = 0, d = -1;
        if (e < E) {
            s = load_edge(eb, fl, base + e);
            unsigned du = (unsigned)load_edge(eb, fl, base + E + e);
            if (du < (unsigned)n) d = (int)du;
        }
        sv[j] = s;
        dv[j] = d;
        rk[j] = (d >= 0) ? atomicAdd(&cnt[d >> shift], 1) : 0;   // rank in bucket
    }
    __syncthreads();
    if (tid < nbuk) {
        int c = cnt[tid];
        gbase[tid] = c ? atomicAdd(&bkcur[tid], c) : 0;          // reserve run
    }
    __syncthreads();
#pragma unroll
    for (int j = 0; j < 16; ++j) {
        if (dv[j] >= 0) {
            int b = dv[j] >> shift;
            pairs[(size_t)(gbase[b] + rk[j])] =
                ((u64)(u32)dv[j] << 32) | (u32)sv[j];
        }
    }
}

// ---------------------------------------------------------------------------
// CSR fill, pass 2: one block per bucket. Per-node cursors live in LDS; the
// ssrc scatter lands inside the bucket's ~16 KB CSR window -> lines fill in
// one XCD's L2 before writeback (full-line writes, ~3-4 MB total).
__global__ __launch_bounds__(256) void scat_kernel(const u64* __restrict__ pairs,
                                                   const int* __restrict__ off,
                                                   int* __restrict__ ssrc,
                                                   int n, int shift) {
    __shared__ int lcur[1024];
    const int d0 = blockIdx.x << shift;
    if (d0 >= n) return;
    int d1 = d0 + (1 << shift);
    if (d1 > n) d1 = n;
    const int nn = d1 - d0;
    const int tid = threadIdx.x;
    for (int j = tid; j < nn; j += 256) lcur[j] = off[d0 + j];
    __syncthreads();
    const int pb = off[d0];
    const int pe = off[d1];
    for (int i = pb + tid; i < pe; i += 256) {
        u64 p = pairs[i];
        unsigned dl = (unsigned)(int)(p >> 32) - (unsigned)d0;
        if (dl < (unsigned)nn) {
            int pos = atomicAdd(&lcur[dl], 1);
            if ((unsigned)pos < (unsigned)pe) ssrc[pos] = (int)(u32)p;
        }
    }
}

// ---------------------------------------------------------------------------
// W (128x128, external dtype) -> Wt bf16 transposed: Wt[c*128+k] = bf16(W[k][c])
__global__ __launch_bounds__(256) void prep_w(const void* __restrict__ W,
                                              const int* __restrict__ flags,
                                              u16* __restrict__ Wt) {
    int tid = blockIdx.x * 256 + threadIdx.x;
    if (tid < 128 * 128) {
        int c = tid >> 7, k = tid & 127;
        Wt[c * 128 + k] = f2bs(ldext(W, flags[1], k * 128 + c));
    }
}

// ---------------------------------------------------------------------------
// MFMA GEMM: hs[v][c] = bf16( dinv[v] * sum_k X[v][k] * W[k][c] )
// mfma_f32_16x16x32_bf16. Block = 4 waves, 64 rows/block; wave = 16 rows x
// 128 cols = 8 col-tiles x 4 K-steps = 32 MFMAs. Wt staged in LDS, row
// stride 136 bf16 (2-way bank aliasing only -> free).
// Verified layouts (learn_hip m89/m91): A[m=lane&15][k=quad*8+j],
// B[n=lane&15][k=quad*8+j], C/D col=lane&15, row=quad*4+reg.
__global__ __launch_bounds__(256) void gemm_mfma(const void* __restrict__ Xv,
                                                 size_t xoff, int x_ext,
                                                 const u16* __restrict__ Wt,
                                                 const int* __restrict__ flags,
                                                 const float* __restrict__ dinv,
                                                 u16* __restrict__ hs, int n) {
    __shared__ u16 Ws[128 * 136];  // Wt[c][k], padded stride 136
    {
        u32* wsu = (u32*)Ws;
        const u32* wtu = (const u32*)Wt;
        for (int i = threadIdx.x; i < 128 * 64; i += 256) {
            int c = i >> 6, kk = i & 63;
            wsu[c * 68 + kk] = wtu[i];
        }
    }
    __syncthreads();

    const int wave = threadIdx.x >> 6;
    const int lane = threadIdx.x & 63;
    const int m = lane & 15;
    const int quad = lane >> 4;
    const int node0 = blockIdx.x * 64 + wave * 16;
    if (node0 >= n) return;

    const int xf32 = x_ext ? flags[1] : 0;   // internal buffers are bf16
    int va = node0 + m;
    if (va > n - 1) va = n - 1;              // clamp; stores guarded

    floatx4 acc[8];
#pragma unroll
    for (int t = 0; t < 8; ++t) acc[t] = (floatx4){0.f, 0.f, 0.f, 0.f};

#pragma unroll
    for (int ks = 0; ks < 4; ++ks) {
        bf16x8 a;
        if (xf32) {
            const float* Xf = (const float*)Xv + xoff + (size_t)va * 128 + ks * 32 + quad * 8;
            float4 x0 = *(const float4*)Xf;
            float4 x1 = *(const float4*)(Xf + 4);
            short8 as;
            as[0] = (short)f2bs(x0.x); as[1] = (short)f2bs(x0.y);
            as[2] = (short)f2bs(x0.z); as[3] = (short)f2bs(x0.w);
            as[4] = (short)f2bs(x1.x); as[5] = (short)f2bs(x1.y);
            as[6] = (short)f2bs(x1.z); as[7] = (short)f2bs(x1.w);
            a = __builtin_bit_cast(bf16x8, as);
        } else {
            const u16* Xb = (const u16*)Xv + xoff + (size_t)va * 128 + ks * 32 + quad * 8;
            a = *(const bf16x8*)Xb;
        }
#pragma unroll
        for (int t = 0; t < 8; ++t) {
            const bf16x8 b = *(const bf16x8*)(Ws + (16 * t + m) * 136 + ks * 32 + quad * 8);
            acc[t] = __builtin_amdgcn_mfma_f32_16x16x32_bf16(a, b, acc[t], 0, 0, 0);
        }
    }

#pragma unroll
    for (int r = 0; r < 4; ++r) {
        int v = node0 + quad * 4 + r;
        if (v < n) {
            float dv = dinv[v];
#pragma unroll
            for (int t = 0; t < 8; ++t)
                hs[(size_t)v * 128 + 16 * t + m] = f2bs(acc[t][r] * dv);
        }
    }
}

// ---------------------------------------------------------------------------
// out[v] = act( dinv[v] * (hs[v] + sum_{u in in(v)} hs[u]) + bias )
// hs: packed bf16 (lane reads u32 = 2 cols). Output: f32 (outf) or bf16 (outb).
__global__ __launch_bounds__(256) void gather_kernel(const u16* __restrict__ hs,
                                                     const int* __restrict__ off,
                                                     const int* __restrict__ deg,
                                                     const int* __restrict__ ssrc,
                                                     const float* __restrict__ dinv,
                                                     const void* __restrict__ bias,
                                                     const int* __restrict__ flags,
                                                     float* __restrict__ outf,
                                                     u16* __restrict__ outb,
                                                     int n, int relu) {
    int w = (blockIdx.x * 256 + threadIdx.x) >> 6;
    int lane = threadIdx.x & 63;
    if (w >= n) return;

    const u32* hsu = (const u32*)hs;         // row stride 64 u32
    u32 p = hsu[(size_t)w * 64 + lane];      // self-loop term
    float ax = lo2f(p), ay = hi2f(p);
    int i = off[w];
    int end = i + deg[w];
    unsigned nm1 = (unsigned)(n - 1);

    float ax1 = 0.f, ay1 = 0.f;
    for (; i + 4 <= end; i += 4) {
        unsigned s0 = (unsigned)ssrc[i];     if (s0 > nm1) s0 = 0;
        unsigned s1 = (unsigned)ssrc[i + 1]; if (s1 > nm1) s1 = 0;
        unsigned s2 = (unsigned)ssrc[i + 2]; if (s2 > nm1) s2 = 0;
        unsigned s3 = (unsigned)ssrc[i + 3]; if (s3 > nm1) s3 = 0;
        u32 v0 = hsu[(size_t)s0 * 64 + lane];
        u32 v1 = hsu[(size_t)s1 * 64 + lane];
        u32 v2 = hsu[(size_t)s2 * 64 + lane];
        u32 v3 = hsu[(size_t)s3 * 64 + lane];
        ax += lo2f(v0) + lo2f(v1);
        ay += hi2f(v0) + hi2f(v1);
        ax1 += lo2f(v2) + lo2f(v3);
        ay1 += hi2f(v2) + hi2f(v3);
    }
    for (; i < end; ++i) {
        unsigned s = (unsigned)ssrc[i];
        if (s > nm1) s = 0;
        u32 v = hsu[(size_t)s * 64 + lane];
        ax += lo2f(v);
        ay += hi2f(v);
    }
    ax += ax1;
    ay += ay1;

    int ffl = flags[1];
    float dv = dinv[w];
    float o0 = dv * ax + ldext(bias, ffl, 2 * lane);
    float o1 = dv * ay + ldext(bias, ffl, 2 * lane + 1);
    if (relu) {
        o0 = fmaxf(o0, 0.f);
        o1 = fmaxf(o1, 0.f);
    }
    if (outf) ((float2*)outf)[(size_t)w * 64 + lane] = make_float2(o0, o1);
    else ((u32*)outb)[(size_t)w * 64 + lane] = (u32)f2bs(o0) | ((u32)f2bs(o1) << 16);
}

// ---------------------------------------------------------------------------
// importance[v] = sum_c final[v][c]*Wc[c] + bc   (f32 in, f32 out)
__global__ __launch_bounds__(256) void importance_kernel(const float* __restrict__ finalf,
                                                         const void* __restrict__ Wc,
                                                         const void* __restrict__ bc,
                                                         const int* __restrict__ flags,
                                                         float* __restrict__ outp, int n) {
    __shared__ float sh[256];
    int tid = threadIdx.x;
    int w = blockIdx.x * 4 + (tid >> 6);
    int lane = tid & 63;
    int ffl = flags[1];
    float contrib = 0.f;
    if (w < n) {
        float2 p = ((const float2*)finalf)[(size_t)w * 64 + lane];
        contrib = p.x * ldext(Wc, ffl, 2 * lane) + p.y * ldext(Wc, ffl, 2 * lane + 1);
    }
    sh[tid] = contrib;
    __syncthreads();
    if (lane == 0 && w < n) {
        float s = 0.f;
        for (int j = 0; j < 64; ++j) s += sh[(tid & 192) + j];
        outp[w] = s + ldext(bc, ffl, 0);
    }
}

// ---------------------------------------------------------------------------
extern "C" void kernel_launch(void* const* d_in, const int* in_sizes, int n_in,
                              void* d_out, int out_size, void* d_ws, size_t ws_size,
                              hipStream_t stream) {
    const int T = 2, C = 128;
    const int N = in_sizes[0] / (T * C);   // 50000
    const int S = in_sizes[1];             // edge buffer reported element count
    const int Emax = S / 4;                // upper bound on edges per timestep

    const void* x_seq = d_in[0];
    const int* edges = (const int*)d_in[1];
    const void* W1 = d_in[2];
    const void* b1 = d_in[3];
    const void* W2 = d_in[4];
    const void* b2 = d_in[5];
    const void* Wc = d_in[6];
    const void* bc = d_in[7];

    // d_out is FLOAT32 (reference output dtype): [imp N][h_t0 N*C][h_t1 N*C]
    float* out = (float*)d_out;
    float* R0 = out + N;
    float* R1 = out + N + (size_t)N * C;

    // workspace ~28 MB (pairs aliases hsb — dead during CSR build)
    char* p = (char*)d_ws;
    auto alloc = [&](size_t bytes) {
        char* r = p;
        p += (bytes + 255) & ~(size_t)255;
        return r;
    };
    int nb = (N + 255) / 256;
    int* flags = (int*)alloc(256);
    int* deg = (int*)alloc((size_t)N * 4);
    int* off = (int*)alloc((size_t)(N + 1) * 4);
    int* btot = (int*)alloc((size_t)nb * 4);
    int* bkcur = (int*)alloc(1024 * 4);
    float* dinv = (float*)alloc((size_t)N * 4);
    int* ssrc = (int*)alloc((size_t)Emax * 4);
    u16* W1t = (u16*)alloc(128 * 128 * 2);
    u16* W2t = (u16*)alloc(128 * 128 * 2);
    u16* hsb = (u16*)alloc((size_t)N * C * 2);   // bf16 scaled GEMM output
    u16* hmb = (u16*)alloc((size_t)N * C * 2);   // bf16 layer-1 activation
    u64* pairs = (u64*)hsb;                      // Emax*8 <= N*C*2; dead overlap

    // dst-range bucketing: ~256 nodes/bucket, <=256 buckets, <=1024 LDS cursors
    int shift = 8;
    while ((((N + (1 << shift) - 1) >> shift) > 256) && shift < 10) ++shift;
    const int NBUK = (N + (1 << shift) - 1) >> shift;

    const int gE = (Emax + 255) / 256;
    const int gP = (Emax + PCHUNK - 1) / PCHUNK;
    const int gN4 = (N + 3) / 4;            // wave-per-node kernels
    const int gG = (N + 63) / 64;           // mfma gemm: block per 64 nodes
    const int gW = (128 * 128 + 255) / 256;

    detect_kernel<<<1, 64, 0, stream>>>(edges, (const u32*)x_seq, flags, S, N);
    prep_w<<<gW, 256, 0, stream>>>(W1, flags, W1t);
    prep_w<<<gW, 256, 0, stream>>>(W2, flags, W2t);

    for (int t = 0; t < T; ++t) {
        float* Rt = (t == 0) ? R0 : R1;     // final output region for this t
        // --- CSR build (shared by both conv layers of this timestep) ---
        hipMemsetAsync(deg, 0, (size_t)N * 4, stream);
        deg_kernel<<<gE, 256, 0, stream>>>(edges, flags, t, deg, N);
        scan_a<<<nb, 256, 0, stream>>>(deg, off, btot, N);
        scan_b<<<1, 256, 0, stream>>>(btot, nb);
        scan_c<<<nb, 256, 0, stream>>>(deg, btot, off, bkcur, dinv, N, shift);
        part_kernel<<<gP, 256, 0, stream>>>(edges, flags, t, bkcur, pairs, N, shift);
        scat_kernel<<<NBUK, 256, 0, stream>>>(pairs, off, ssrc, N, shift);

        // --- layer 1: hsb = dinv*(X_t @ W1); hmb = relu(gather)+b1 (bf16) ---
        gemm_mfma<<<gG, 256, 0, stream>>>(x_seq, (size_t)t * N * C, 1, W1t, flags,
                                          dinv, hsb, N);
        gather_kernel<<<gN4, 256, 0, stream>>>(hsb, off, deg, ssrc, dinv, b1, flags,
                                               (float*)nullptr, hmb, N, 1);

        // --- layer 2: hsb = dinv*(hmb @ W2); Rt = gather + b2 (f32) ---
        gemm_mfma<<<gG, 256, 0, stream>>>(hmb, 0, 0, W2t, flags, dinv, hsb, N);
        gather_kernel<<<gN4, 256, 0, stream>>>(hsb, off, deg, ssrc, dinv, b2, flags,
                                               Rt, (u16*)nullptr, N, 0);
    }

    importance_kernel<<<gN4, 256, 0, stream>>>(R1, Wc, bc, flags, out, N);
}

// Round 2
// 394.656 us; speedup vs baseline: 1.3179x; 1.1808x over previous
//
#include <hip/hip_runtime.h>
#include <hip/hip_bf16.h>

typedef unsigned int u32;
typedef unsigned short u16;
typedef unsigned long long u64;
typedef __bf16 bf16x8 __attribute__((ext_vector_type(8)));
typedef short short8 __attribute__((ext_vector_type(8)));
typedef float floatx4 __attribute__((ext_vector_type(4)));

__device__ inline float b2f(u16 b) { return __uint_as_float((u32)b << 16); }
__device__ inline float lo2f(u32 p) { return __uint_as_float(p << 16); }
__device__ inline float hi2f(u32 p) { return __uint_as_float(p & 0xffff0000u); }
__device__ inline u16 f2bs(float f) {   // RNE f32 -> bf16 bits
    __hip_bfloat16 h = __float2bfloat16(f);
    return *reinterpret_cast<u16*>(&h);
}
// element i of an external float array: f32 (fl=1) or packed bf16 (fl=0)
__device__ inline float ldext(const void* p, int fl, int i) {
    return fl ? ((const float*)p)[i] : b2f(((const u16*)p)[i]);
}

// ---------------------------------------------------------------------------
// flags[0]: edge stride (1 = int64 layout, 0 = int32)
// flags[1]: float inputs are f32 (1) or packed bf16 (0)
// flags[2]: E (edges per timestep), decided by probing data extent
__global__ __launch_bounds__(64) void detect_kernel(const int* __restrict__ eb,
                                                    const u32* __restrict__ xw,
                                                    int* __restrict__ flags,
                                                    int S, int n) {
    __shared__ int sh[64 * 3];
    int lane = threadIdx.x & 63;
    int zc = 0, explo = 0;
#pragma unroll
    for (int r = 0; r < 4; ++r) {
        int i = 64 * r + lane;
        zc += (eb[2 * i + 1] == 0) ? 1 : 0;   // int64: odd dwords are hi-words = 0
        u32 w = xw[i];
        int e = (int)((w >> 7) & 0xFF);       // exponent field of LOW half as bf16
        explo += (e >= 96 && e <= 140) ? 1 : 0;
    }
    sh[lane] = zc;
    sh[64 + lane] = explo;
    __syncthreads();
    int fl = 0;
    {
        int z = 0;
        for (int j = 0; j < 64; ++j) z += sh[j];
        fl = (z > 200) ? 1 : 0;   // wave-uniform
    }
    // probe logical indices [S/2, S/2+256): valid node ids => S counts logical
    // elements (E = S/4); garbage => S counts int32 words (E = S/8).
    int vc = 0;
#pragma unroll
    for (int r = 0; r < 4; ++r) {
        int li = S / 2 + 64 * r + lane;
        int v = fl ? eb[2 * li] : eb[li];
        vc += ((unsigned)v < (unsigned)n) ? 1 : 0;
    }
    sh[128 + lane] = vc;
    __syncthreads();
    if (lane == 0) {
        int vtot = 0, etot = 0;
        for (int j = 0; j < 64; ++j) vtot += sh[128 + j];
        for (int j = 0; j < 64; ++j) etot += sh[64 + j];
        flags[0] = fl;
        flags[1] = (etot >= 192) ? 0 : 1;   // bf16-packed signature else f32
        flags[2] = (vtot >= 240) ? (S / 4) : (S / 8);
    }
}

__device__ inline int load_edge(const int* eb, int fl, int idx) {
    return eb[fl ? (idx << 1) : idx];
}

// ---------------------------------------------------------------------------
// degree over BOTH timesteps in one pass: global node id g = t*N + dst
__global__ __launch_bounds__(256) void deg_kernel(const int* __restrict__ eb,
                                                  const int* __restrict__ flags,
                                                  int* __restrict__ deg, int n) {
    int E = flags[2];
    int e = blockIdx.x * 256 + threadIdx.x;
    if (e < 2 * E) {
        int t = (e >= E) ? 1 : 0;
        int le = e - t * E;
        unsigned d = (unsigned)load_edge(eb, flags[0], t * 2 * E + E + le);
        if (d < (unsigned)n) atomicAdd(&deg[t * n + d], 1);
    }
}

// ---------------------------------------------------------------------------
// 3-phase exclusive scan of deg (length n2=2N) -> off, bucket cursors, dinv
__global__ __launch_bounds__(256) void scan_a(const int* __restrict__ deg,
                                              int* __restrict__ off,
                                              int* __restrict__ btot, int n2) {
    __shared__ int tmp[256];
    int t = threadIdx.x;
    int i = blockIdx.x * 256 + t;
    int d = (i < n2) ? deg[i] : 0;
    int val = d;
    tmp[t] = val;
    __syncthreads();
    for (int o = 1; o < 256; o <<= 1) {
        int add = (t >= o) ? tmp[t - o] : 0;
        __syncthreads();
        val += add;
        tmp[t] = val;
        __syncthreads();
    }
    if (i < n2) off[i] = val - d;
    if (t == 255) btot[blockIdx.x] = val;
}

// single block, loops over chunks of 256 block-totals with running carry
__global__ __launch_bounds__(256) void scan_b(int* __restrict__ btot, int nb) {
    __shared__ int tmp[256];
    int t = threadIdx.x;
    int carry = 0;
    for (int c0 = 0; c0 < nb; c0 += 256) {
        int d = (c0 + t < nb) ? btot[c0 + t] : 0;
        int val = d;
        tmp[t] = val;
        __syncthreads();
        for (int o = 1; o < 256; o <<= 1) {
            int add = (t >= o) ? tmp[t - o] : 0;
            __syncthreads();
            val += add;
            tmp[t] = val;
            __syncthreads();
        }
        if (c0 + t < nb) btot[c0 + t] = val - d + carry;
        int tot = tmp[255];
        __syncthreads();
        carry += tot;
    }
}

__global__ __launch_bounds__(256) void scan_c(const int* __restrict__ deg,
                                              const int* __restrict__ btot,
                                              int* __restrict__ off,
                                              int* __restrict__ bkcur,
                                              float* __restrict__ dinv,
                                              int n2, int shift) {
    int i = blockIdx.x * 256 + threadIdx.x;
    if (i < n2) {
        int o = off[i] + btot[blockIdx.x];
        off[i] = o;
        if ((i & ((1 << shift) - 1)) == 0) bkcur[i >> shift] = o;  // bucket start
        if (i == n2 - 1) off[n2] = o + deg[i];                     // total valid edges
        dinv[i] = rsqrtf((float)(deg[i] + 1));  // +1 = self-loop
    }
}

// ---------------------------------------------------------------------------
// CSR fill, pass 1 (both timesteps): partition edges into global-dst-range
// buckets. Each block counts per-bucket occupancy in LDS, reserves a
// contiguous run per bucket with ONE global atomicAdd, writes (g,src) u64
// pairs in ~150 B contiguous runs -> near-full cache lines.
#define PCHUNK 4096
__global__ __launch_bounds__(256) void part_kernel(const int* __restrict__ eb,
                                                   const int* __restrict__ flags,
                                                   int* __restrict__ bkcur,
                                                   u64* __restrict__ pairs,
                                                   int n, int shift) {
    __shared__ int cnt[512];
    __shared__ int gbase[512];
    const int E = flags[2];
    const int fl = flags[0];
    const int nbuk = (2 * n + (1 << shift) - 1) >> shift;
    const int tid = threadIdx.x;
    for (int i = tid; i < nbuk; i += 256) cnt[i] = 0;
    __syncthreads();
    const int e0 = blockIdx.x * PCHUNK;
    int sv[16], gv[16], rk[16];
#pragma unroll
    for (int j = 0; j < 16; ++j) {
        int e = e0 + j * 256 + tid;
        int s = 0, g = -1;
        if (e < 2 * E) {
            int t = (e >= E) ? 1 : 0;
            int le = e - t * E;
            s = load_edge(eb, fl, t * 2 * E + le);
            unsigned du = (unsigned)load_edge(eb, fl, t * 2 * E + E + le);
            if (du < (unsigned)n) g = t * n + (int)du;
        }
        sv[j] = s;
        gv[j] = g;
        rk[j] = (g >= 0) ? atomicAdd(&cnt[g >> shift], 1) : 0;   // rank in bucket
    }
    __syncthreads();
    for (int b = tid; b < nbuk; b += 256) {
        int c = cnt[b];
        gbase[b] = c ? atomicAdd(&bkcur[b], c) : 0;              // reserve run
    }
    __syncthreads();
#pragma unroll
    for (int j = 0; j < 16; ++j) {
        if (gv[j] >= 0) {
            int b = gv[j] >> shift;
            pairs[(size_t)(gbase[b] + rk[j])] =
                ((u64)(u32)gv[j] << 32) | (u32)sv[j];
        }
    }
}

// ---------------------------------------------------------------------------
// CSR fill, pass 2: one block per bucket. Per-node cursors in LDS; the ssrc
// scatter lands inside the bucket's ~16 KB CSR window -> full-line writes.
__global__ __launch_bounds__(256) void scat_kernel(const u64* __restrict__ pairs,
                                                   const int* __restrict__ off,
                                                   int* __restrict__ ssrc,
                                                   int n2, int shift) {
    __shared__ int lcur[1024];
    const int d0 = blockIdx.x << shift;
    if (d0 >= n2) return;
    int d1 = d0 + (1 << shift);
    if (d1 > n2) d1 = n2;
    const int nn = d1 - d0;
    const int tid = threadIdx.x;
    for (int j = tid; j < nn; j += 256) lcur[j] = off[d0 + j];
    __syncthreads();
    const int pb = off[d0];
    const int pe = off[d1];
    for (int i = pb + tid; i < pe; i += 256) {
        u64 p = pairs[i];
        unsigned dl = (unsigned)(int)(p >> 32) - (unsigned)d0;
        if (dl < (unsigned)nn) {
            int pos = atomicAdd(&lcur[dl], 1);
            if ((unsigned)pos < (unsigned)pe) ssrc[pos] = (int)(u32)p;
        }
    }
}

// ---------------------------------------------------------------------------
// W1,W2 (128x128, external dtype) -> bf16 transposed: Wt[c*128+k] = bf16(W[k][c])
__global__ __launch_bounds__(256) void prep_w(const void* __restrict__ W1,
                                              const void* __restrict__ W2,
                                              const int* __restrict__ flags,
                                              u16* __restrict__ W1t,
                                              u16* __restrict__ W2t) {
    int tid = blockIdx.x * 256 + threadIdx.x;
    if (tid < 2 * 128 * 128) {
        int which = tid >> 14;
        int r = tid & 16383;
        const void* W = which ? W2 : W1;
        u16* Wt = which ? W2t : W1t;
        int c = r >> 7, k = r & 127;
        Wt[c * 128 + k] = f2bs(ldext(W, flags[1], k * 128 + c));
    }
}

// ---------------------------------------------------------------------------
// MFMA GEMM: hs[v][c] = bf16( dinv[v] * sum_k X[v][k] * W[k][c] )
// mfma_f32_16x16x32_bf16. Block = 4 waves, 64 rows/block; wave = 16 rows x
// 128 cols = 8 col-tiles x 4 K-steps = 32 MFMAs. Wt staged in LDS, row
// stride 136 bf16 (2-way bank aliasing only -> free).
// Verified layouts (learn_hip m89/m91): A[m=lane&15][k=quad*8+j],
// B[n=lane&15][k=quad*8+j], C/D col=lane&15, row=quad*4+reg.
__global__ __launch_bounds__(256) void gemm_mfma(const void* __restrict__ Xv,
                                                 size_t xoff, int x_ext,
                                                 const u16* __restrict__ Wt,
                                                 const int* __restrict__ flags,
                                                 const float* __restrict__ dinv,
                                                 u16* __restrict__ hs, int n) {
    __shared__ u16 Ws[128 * 136];  // Wt[c][k], padded stride 136
    {
        u32* wsu = (u32*)Ws;
        const u32* wtu = (const u32*)Wt;
        for (int i = threadIdx.x; i < 128 * 64; i += 256) {
            int c = i >> 6, kk = i & 63;
            wsu[c * 68 + kk] = wtu[i];
        }
    }
    __syncthreads();

    const int wave = threadIdx.x >> 6;
    const int lane = threadIdx.x & 63;
    const int m = lane & 15;
    const int quad = lane >> 4;
    const int node0 = blockIdx.x * 64 + wave * 16;
    if (node0 >= n) return;

    const int xf32 = x_ext ? flags[1] : 0;   // internal buffers are bf16
    int va = node0 + m;
    if (va > n - 1) va = n - 1;              // clamp; stores guarded

    floatx4 acc[8];
#pragma unroll
    for (int t = 0; t < 8; ++t) acc[t] = (floatx4){0.f, 0.f, 0.f, 0.f};

#pragma unroll
    for (int ks = 0; ks < 4; ++ks) {
        bf16x8 a;
        if (xf32) {
            const float* Xf = (const float*)Xv + xoff + (size_t)va * 128 + ks * 32 + quad * 8;
            float4 x0 = *(const float4*)Xf;
            float4 x1 = *(const float4*)(Xf + 4);
            short8 as;
            as[0] = (short)f2bs(x0.x); as[1] = (short)f2bs(x0.y);
            as[2] = (short)f2bs(x0.z); as[3] = (short)f2bs(x0.w);
            as[4] = (short)f2bs(x1.x); as[5] = (short)f2bs(x1.y);
            as[6] = (short)f2bs(x1.z); as[7] = (short)f2bs(x1.w);
            a = __builtin_bit_cast(bf16x8, as);
        } else {
            const u16* Xb = (const u16*)Xv + xoff + (size_t)va * 128 + ks * 32 + quad * 8;
            a = *(const bf16x8*)Xb;
        }
#pragma unroll
        for (int t = 0; t < 8; ++t) {
            const bf16x8 b = *(const bf16x8*)(Ws + (16 * t + m) * 136 + ks * 32 + quad * 8);
            acc[t] = __builtin_amdgcn_mfma_f32_16x16x32_bf16(a, b, acc[t], 0, 0, 0);
        }
    }

#pragma unroll
    for (int r = 0; r < 4; ++r) {
        int v = node0 + quad * 4 + r;
        if (v < n) {
            float dv = dinv[v];
#pragma unroll
            for (int t = 0; t < 8; ++t)
                hs[(size_t)v * 128 + 16 * t + m] = f2bs(acc[t][r] * dv);
        }
    }
}

// ---------------------------------------------------------------------------
// out[v] = act( dinv[v] * (hs[v] + sum_{u in in(v)} hs[u]) + bias )
// hs: packed bf16 (lane reads u32 = 2 cols). Output: f32 (outf) or bf16 (outb).
// 8-deep unrolled edge loop: 8 independent row gathers in flight per wave.
// off/dinv passed pre-offset by t*N (off values are global ssrc positions).
// If imp != null, also computes importance[v] = final[v] . Wc + bc (fused).
__global__ __launch_bounds__(256) void gather_kernel(const u16* __restrict__ hs,
                                                     const int* __restrict__ off,
                                                     const int* __restrict__ ssrc,
                                                     const float* __restrict__ dinv,
                                                     const void* __restrict__ bias,
                                                     const int* __restrict__ flags,
                                                     float* __restrict__ outf,
                                                     u16* __restrict__ outb,
                                                     const void* __restrict__ Wc,
                                                     const void* __restrict__ bc,
                                                     float* __restrict__ imp,
                                                     int n, int relu) {
    int w = (blockIdx.x * 256 + threadIdx.x) >> 6;
    int lane = threadIdx.x & 63;
    if (w >= n) return;

    const u32* hsu = (const u32*)hs;         // row stride 64 u32
    u32 p = hsu[(size_t)w * 64 + lane];      // self-loop term
    float ax = lo2f(p), ay = hi2f(p);
    int i = __builtin_amdgcn_readfirstlane(off[w]);
    int end = __builtin_amdgcn_readfirstlane(off[w + 1]);
    unsigned nm1 = (unsigned)(n - 1);

    float bx = 0.f, by = 0.f, cx = 0.f, cy = 0.f, dx = 0.f, dy = 0.f;
    for (; i + 8 <= end; i += 8) {
        unsigned s0 = (unsigned)ssrc[i];     if (s0 > nm1) s0 = 0;
        unsigned s1 = (unsigned)ssrc[i + 1]; if (s1 > nm1) s1 = 0;
        unsigned s2 = (unsigned)ssrc[i + 2]; if (s2 > nm1) s2 = 0;
        unsigned s3 = (unsigned)ssrc[i + 3]; if (s3 > nm1) s3 = 0;
        unsigned s4 = (unsigned)ssrc[i + 4]; if (s4 > nm1) s4 = 0;
        unsigned s5 = (unsigned)ssrc[i + 5]; if (s5 > nm1) s5 = 0;
        unsigned s6 = (unsigned)ssrc[i + 6]; if (s6 > nm1) s6 = 0;
        unsigned s7 = (unsigned)ssrc[i + 7]; if (s7 > nm1) s7 = 0;
        u32 v0 = hsu[(size_t)s0 * 64 + lane];
        u32 v1 = hsu[(size_t)s1 * 64 + lane];
        u32 v2 = hsu[(size_t)s2 * 64 + lane];
        u32 v3 = hsu[(size_t)s3 * 64 + lane];
        u32 v4 = hsu[(size_t)s4 * 64 + lane];
        u32 v5 = hsu[(size_t)s5 * 64 + lane];
        u32 v6 = hsu[(size_t)s6 * 64 + lane];
        u32 v7 = hsu[(size_t)s7 * 64 + lane];
        ax += lo2f(v0); ay += hi2f(v0);
        bx += lo2f(v1); by += hi2f(v1);
        cx += lo2f(v2); cy += hi2f(v2);
        dx += lo2f(v3); dy += hi2f(v3);
        ax += lo2f(v4); ay += hi2f(v4);
        bx += lo2f(v5); by += hi2f(v5);
        cx += lo2f(v6); cy += hi2f(v6);
        dx += lo2f(v7); dy += hi2f(v7);
    }
    for (; i + 4 <= end; i += 4) {
        unsigned s0 = (unsigned)ssrc[i];     if (s0 > nm1) s0 = 0;
        unsigned s1 = (unsigned)ssrc[i + 1]; if (s1 > nm1) s1 = 0;
        unsigned s2 = (unsigned)ssrc[i + 2]; if (s2 > nm1) s2 = 0;
        unsigned s3 = (unsigned)ssrc[i + 3]; if (s3 > nm1) s3 = 0;
        u32 v0 = hsu[(size_t)s0 * 64 + lane];
        u32 v1 = hsu[(size_t)s1 * 64 + lane];
        u32 v2 = hsu[(size_t)s2 * 64 + lane];
        u32 v3 = hsu[(size_t)s3 * 64 + lane];
        ax += lo2f(v0); ay += hi2f(v0);
        bx += lo2f(v1); by += hi2f(v1);
        cx += lo2f(v2); cy += hi2f(v2);
        dx += lo2f(v3); dy += hi2f(v3);
    }
    for (; i < end; ++i) {
        unsigned s = (unsigned)ssrc[i];
        if (s > nm1) s = 0;
        u32 v = hsu[(size_t)s * 64 + lane];
        ax += lo2f(v);
        ay += hi2f(v);
    }
    ax += bx + cx + dx;
    ay += by + cy + dy;

    int ffl = flags[1];
    float dv = dinv[w];
    float o0 = dv * ax + ldext(bias, ffl, 2 * lane);
    float o1 = dv * ay + ldext(bias, ffl, 2 * lane + 1);
    if (relu) {
        o0 = fmaxf(o0, 0.f);
        o1 = fmaxf(o1, 0.f);
    }
    if (outf) ((float2*)outf)[(size_t)w * 64 + lane] = make_float2(o0, o1);
    else ((u32*)outb)[(size_t)w * 64 + lane] = (u32)f2bs(o0) | ((u32)f2bs(o1) << 16);

    if (imp) {   // fused importance: wave-reduce final[w] . Wc
        float cb = o0 * ldext(Wc, ffl, 2 * lane) + o1 * ldext(Wc, ffl, 2 * lane + 1);
        cb += __shfl_xor(cb, 32);
        cb += __shfl_xor(cb, 16);
        cb += __shfl_xor(cb, 8);
        cb += __shfl_xor(cb, 4);
        cb += __shfl_xor(cb, 2);
        cb += __shfl_xor(cb, 1);
        if (lane == 0) imp[w] = cb + ldext(bc, ffl, 0);
    }
}

// ---------------------------------------------------------------------------
extern "C" void kernel_launch(void* const* d_in, const int* in_sizes, int n_in,
                              void* d_out, int out_size, void* d_ws, size_t ws_size,
                              hipStream_t stream) {
    const int T = 2, C = 128;
    const int N = in_sizes[0] / (T * C);   // 50000
    const int S = in_sizes[1];             // edge buffer reported element count
    const int Emax = S / 4;                // upper bound on edges per timestep
    const int N2 = 2 * N;                  // global node space (both timesteps)

    const void* x_seq = d_in[0];
    const int* edges = (const int*)d_in[1];
    const void* W1 = d_in[2];
    const void* b1 = d_in[3];
    const void* W2 = d_in[4];
    const void* b2 = d_in[5];
    const void* Wc = d_in[6];
    const void* bc = d_in[7];

    // d_out is FLOAT32 (reference output dtype): [imp N][h_t0 N*C][h_t1 N*C]
    float* out = (float*)d_out;
    float* R0 = out + N;
    float* R1 = out + N + (size_t)N * C;

    // workspace (~46 MB); pairs aliases hsb — dead before first GEMM writes it
    char* p = (char*)d_ws;
    auto alloc = [&](size_t bytes) {
        char* r = p;
        p += (bytes + 255) & ~(size_t)255;
        return r;
    };
    int nb2 = (N2 + 255) / 256;
    int* flags = (int*)alloc(256);
    int* deg = (int*)alloc((size_t)N2 * 4);
    int* off = (int*)alloc((size_t)(N2 + 1) * 4);
    int* btot = (int*)alloc((size_t)nb2 * 4);
    int* bkcur = (int*)alloc(512 * 4);
    float* dinv = (float*)alloc((size_t)N2 * 4);
    int* ssrc = (int*)alloc((size_t)2 * Emax * 4);
    u16* W1t = (u16*)alloc(128 * 128 * 2);
    u16* W2t = (u16*)alloc(128 * 128 * 2);
    u16* hsb = (u16*)alloc((size_t)2 * Emax * 8 > (size_t)N * C * 2
                               ? (size_t)2 * Emax * 8 : (size_t)N * C * 2);
    u16* hmb = (u16*)alloc((size_t)N * C * 2);   // bf16 layer-1 activation
    u64* pairs = (u64*)hsb;                      // dead overlap with GEMM output

    // dst-range bucketing over 2N nodes: <=512 buckets, <=1024 LDS cursors
    int shift = 8;
    while ((((N2 + (1 << shift) - 1) >> shift) > 512) && shift < 10) ++shift;
    const int NBUK = (N2 + (1 << shift) - 1) >> shift;

    const int gE2 = (2 * Emax + 255) / 256;
    const int gP = (2 * Emax + PCHUNK - 1) / PCHUNK;
    const int gN4 = (N + 3) / 4;            // wave-per-node kernels
    const int gG = (N + 63) / 64;           // mfma gemm: block per 64 nodes
    const int gW = (2 * 128 * 128 + 255) / 256;

    detect_kernel<<<1, 64, 0, stream>>>(edges, (const u32*)x_seq, flags, S, N);
    prep_w<<<gW, 256, 0, stream>>>(W1, W2, flags, W1t, W2t);

    // --- CSR build for BOTH timesteps in one pass (global ids g = t*N+dst) ---
    hipMemsetAsync(deg, 0, (size_t)N2 * 4, stream);
    deg_kernel<<<gE2, 256, 0, stream>>>(edges, flags, deg, N);
    scan_a<<<nb2, 256, 0, stream>>>(deg, off, btot, N2);
    scan_b<<<1, 256, 0, stream>>>(btot, nb2);
    scan_c<<<nb2, 256, 0, stream>>>(deg, btot, off, bkcur, dinv, N2, shift);
    part_kernel<<<gP, 256, 0, stream>>>(edges, flags, bkcur, pairs, N, shift);
    scat_kernel<<<NBUK, 256, 0, stream>>>(pairs, off, ssrc, N2, shift);

    for (int t = 0; t < T; ++t) {
        float* Rt = (t == 0) ? R0 : R1;     // final output region for this t
        const int* off_t = off + (size_t)t * N;
        const float* dinv_t = dinv + (size_t)t * N;

        // --- layer 1: hsb = dinv*(X_t @ W1); hmb = relu(gather)+b1 (bf16) ---
        gemm_mfma<<<gG, 256, 0, stream>>>(x_seq, (size_t)t * N * C, 1, W1t, flags,
                                          dinv_t, hsb, N);
        gather_kernel<<<gN4, 256, 0, stream>>>(hsb, off_t, ssrc, dinv_t, b1, flags,
                                               (float*)nullptr, hmb,
                                               nullptr, nullptr, (float*)nullptr,
                                               N, 1);

        // --- layer 2: hsb = dinv*(hmb @ W2); Rt = gather + b2 (f32) ---
        gemm_mfma<<<gG, 256, 0, stream>>>(hmb, 0, 0, W2t, flags, dinv_t, hsb, N);
        gather_kernel<<<gN4, 256, 0, stream>>>(hsb, off_t, ssrc, dinv_t, b2, flags,
                                               Rt, (u16*)nullptr,
                                               Wc, bc, (t == 1) ? out : (float*)nullptr,
                                               N, 0);
    }
}

// Round 3
// 327.759 us; speedup vs baseline: 1.5869x; 1.2041x over previous
//
#include <hip/hip_runtime.h>
#include <hip/hip_bf16.h>

typedef unsigned int u32;
typedef unsigned short u16;
typedef unsigned long long u64;
typedef __bf16 bf16x8 __attribute__((ext_vector_type(8)));
typedef short short8 __attribute__((ext_vector_type(8)));
typedef float floatx4 __attribute__((ext_vector_type(4)));

__device__ inline float b2f(u16 b) { return __uint_as_float((u32)b << 16); }
__device__ inline float lo2f(u32 p) { return __uint_as_float(p << 16); }
__device__ inline float hi2f(u32 p) { return __uint_as_float(p & 0xffff0000u); }
__device__ inline u16 f2bs(float f) {   // RNE f32 -> bf16 bits
    __hip_bfloat16 h = __float2bfloat16(f);
    return *reinterpret_cast<u16*>(&h);
}
// element i of an external float array: f32 (fl=1) or packed bf16 (fl=0)
__device__ inline float ldext(const void* p, int fl, int i) {
    return fl ? ((const float*)p)[i] : b2f(((const u16*)p)[i]);
}

// ---------------------------------------------------------------------------
// flags[0]: edge stride (1 = int64 layout, 0 = int32)
// flags[1]: float inputs are f32 (1) or packed bf16 (0)
// flags[2]: E (edges per timestep), decided by probing data extent
__global__ __launch_bounds__(64) void detect_kernel(const int* __restrict__ eb,
                                                    const u32* __restrict__ xw,
                                                    int* __restrict__ flags,
                                                    int S, int n) {
    __shared__ int sh[64 * 3];
    int lane = threadIdx.x & 63;
    int zc = 0, explo = 0;
#pragma unroll
    for (int r = 0; r < 4; ++r) {
        int i = 64 * r + lane;
        zc += (eb[2 * i + 1] == 0) ? 1 : 0;   // int64: odd dwords are hi-words = 0
        u32 w = xw[i];
        int e = (int)((w >> 7) & 0xFF);       // exponent field of LOW half as bf16
        explo += (e >= 96 && e <= 140) ? 1 : 0;
    }
    sh[lane] = zc;
    sh[64 + lane] = explo;
    __syncthreads();
    int fl = 0;
    {
        int z = 0;
        for (int j = 0; j < 64; ++j) z += sh[j];
        fl = (z > 200) ? 1 : 0;   // wave-uniform
    }
    // probe logical indices [S/2, S/2+256): valid node ids => S counts logical
    // elements (E = S/4); garbage => S counts int32 words (E = S/8).
    int vc = 0;
#pragma unroll
    for (int r = 0; r < 4; ++r) {
        int li = S / 2 + 64 * r + lane;
        int v = fl ? eb[2 * li] : eb[li];
        vc += ((unsigned)v < (unsigned)n) ? 1 : 0;
    }
    sh[128 + lane] = vc;
    __syncthreads();
    if (lane == 0) {
        int vtot = 0, etot = 0;
        for (int j = 0; j < 64; ++j) vtot += sh[128 + j];
        for (int j = 0; j < 64; ++j) etot += sh[64 + j];
        flags[0] = fl;
        flags[1] = (etot >= 192) ? 0 : 1;   // bf16-packed signature else f32
        flags[2] = (vtot >= 240) ? (S / 4) : (S / 8);
    }
}

__device__ inline int load_edge(const int* eb, int fl, int idx) {
    return eb[fl ? (idx << 1) : idx];
}

// ---------------------------------------------------------------------------
// CSR build pass 1 (both timesteps, NO pre-computed degrees): partition edges
// into global-dst-range buckets with FIXED capacity capP. Per-block LDS
// histogram -> one global atomicAdd per bucket to reserve a contiguous run ->
// (g,src) u64 pairs written in ~150 B runs (near-full cache lines).
// Degrees are recovered later from the pairs themselves (scat_kernel), which
// kills deg_kernel's 50 MB of scattered-atomic HBM writebacks.
#define PCHUNK 4096
__global__ __launch_bounds__(256) void part_kernel(const int* __restrict__ eb,
                                                   const int* __restrict__ flags,
                                                   int* __restrict__ bkcnt,
                                                   u64* __restrict__ pairs,
                                                   int n, int shift, int capP) {
    __shared__ int cnt[512];
    __shared__ int gbase[512];
    const int E = flags[2];
    const int fl = flags[0];
    const int nbuk = (2 * n + (1 << shift) - 1) >> shift;
    const int tid = threadIdx.x;
    for (int i = tid; i < nbuk; i += 256) cnt[i] = 0;
    __syncthreads();
    const int e0 = blockIdx.x * PCHUNK;
    int sv[16], gv[16], rk[16];
#pragma unroll
    for (int j = 0; j < 16; ++j) {
        int e = e0 + j * 256 + tid;
        int s = 0, g = -1;
        if (e < 2 * E) {
            int t = (e >= E) ? 1 : 0;
            int le = e - t * E;
            s = load_edge(eb, fl, t * 2 * E + le);
            unsigned du = (unsigned)load_edge(eb, fl, t * 2 * E + E + le);
            if (du < (unsigned)n) g = t * n + (int)du;
        }
        sv[j] = s;
        gv[j] = g;
        rk[j] = (g >= 0) ? atomicAdd(&cnt[g >> shift], 1) : 0;   // rank in bucket
    }
    __syncthreads();
    for (int b = tid; b < nbuk; b += 256) {
        int c = cnt[b];
        gbase[b] = c ? atomicAdd(&bkcnt[b], c) : 0;              // reserve run
    }
    __syncthreads();
#pragma unroll
    for (int j = 0; j < 16; ++j) {
        if (gv[j] >= 0) {
            int b = gv[j] >> shift;
            int idx = gbase[b] + rk[j];
            if (idx < capP)                                      // overflow guard
                pairs[(size_t)b * capP + idx] =
                    ((u64)(u32)gv[j] << 32) | (u32)sv[j];
        }
    }
}

// ---------------------------------------------------------------------------
// Exclusive scan of min(bkcnt,capP) over nbuk (<=512) buckets -> dense ssrc
// bucket bases. Single block, chunked with carry.
__global__ __launch_bounds__(256) void scan_bk(const int* __restrict__ bkcnt,
                                               int* __restrict__ bkbase,
                                               int nbuk, int capP) {
    __shared__ int tmp[256];
    int t = threadIdx.x;
    int carry = 0;
    for (int c0 = 0; c0 < nbuk; c0 += 256) {
        int d = 0;
        if (c0 + t < nbuk) {
            d = bkcnt[c0 + t];
            if (d > capP) d = capP;
        }
        int val = d;
        tmp[t] = val;
        __syncthreads();
        for (int o = 1; o < 256; o <<= 1) {
            int add = (t >= o) ? tmp[t - o] : 0;
            __syncthreads();
            val += add;
            tmp[t] = val;
            __syncthreads();
        }
        if (c0 + t < nbuk) bkbase[c0 + t] = val - d + carry;
        int tot = tmp[255];
        __syncthreads();
        carry += tot;
    }
}

// ---------------------------------------------------------------------------
// CSR build pass 2: one block per bucket. LDS histogram of the bucket's pairs
// gives local degrees; LDS exclusive scan gives local CSR offsets; deg/off/
// dinv written coalesced (full lines); then in-bucket ssrc scatter (~16 KB
// window, L2-hot -> full-line writebacks).
__global__ __launch_bounds__(256) void scat_kernel(const u64* __restrict__ pairs,
                                                   const int* __restrict__ bkcnt,
                                                   const int* __restrict__ bkbase,
                                                   int* __restrict__ deg,
                                                   int* __restrict__ off,
                                                   float* __restrict__ dinv,
                                                   int* __restrict__ ssrc,
                                                   int n2, int shift, int capP) {
    __shared__ int hist[1024];   // histogram, then reused as scatter cursors
    __shared__ int lscan[256];
    const int b = blockIdx.x;
    const int d0 = b << shift;
    if (d0 >= n2) return;
    int nn = (1 << shift);
    if (d0 + nn > n2) nn = n2 - d0;
    const int tid = threadIdx.x;
    for (int j = tid; j < nn; j += 256) hist[j] = 0;
    __syncthreads();
    int cnt = bkcnt[b];
    if (cnt > capP) cnt = capP;
    const u64* pb = pairs + (size_t)b * capP;
    for (int i = tid; i < cnt; i += 256) {
        unsigned dl = (unsigned)(int)(pb[i] >> 32) - (unsigned)d0;
        if (dl < (unsigned)nn) atomicAdd(&hist[dl], 1);
    }
    __syncthreads();
    // exclusive scan of hist[0..nn): thread t owns elements [4t, 4t+4)
    int base4 = tid * 4;
    int s0 = 0, s1 = 0, s2 = 0, s3 = 0;
    if (base4 < nn) {
        s0 = hist[base4];
        s1 = (base4 + 1 < nn) ? hist[base4 + 1] : 0;
        s2 = (base4 + 2 < nn) ? hist[base4 + 2] : 0;
        s3 = (base4 + 3 < nn) ? hist[base4 + 3] : 0;
    }
    int tsum = s0 + s1 + s2 + s3;
    lscan[tid] = tsum;
    __syncthreads();
    int val = tsum;
    for (int o = 1; o < 256; o <<= 1) {
        int add = (tid >= o) ? lscan[tid - o] : 0;
        __syncthreads();
        val += add;
        lscan[tid] = val;
        __syncthreads();
    }
    int texcl = val - tsum;                  // exclusive prefix of this thread's 4
    const int gb = bkbase[b];
    if (base4 < nn) {
        int g = d0 + base4;
        int o0 = gb + texcl;
        deg[g] = s0; off[g] = o0; dinv[g] = rsqrtf((float)(s0 + 1));
        hist[base4] = o0;
        if (base4 + 1 < nn) {
            int o1 = o0 + s0;
            deg[g + 1] = s1; off[g + 1] = o1; dinv[g + 1] = rsqrtf((float)(s1 + 1));
            hist[base4 + 1] = o1;
        }
        if (base4 + 2 < nn) {
            int o2 = o0 + s0 + s1;
            deg[g + 2] = s2; off[g + 2] = o2; dinv[g + 2] = rsqrtf((float)(s2 + 1));
            hist[base4 + 2] = o2;
        }
        if (base4 + 3 < nn) {
            int o3 = o0 + s0 + s1 + s2;
            deg[g + 3] = s3; off[g + 3] = o3; dinv[g + 3] = rsqrtf((float)(s3 + 1));
            hist[base4 + 3] = o3;
        }
    }
    __syncthreads();
    const int limit = gb + cnt;
    for (int i = tid; i < cnt; i += 256) {
        u64 p = pb[i];
        unsigned dl = (unsigned)(int)(p >> 32) - (unsigned)d0;
        if (dl < (unsigned)nn) {
            int pos = atomicAdd(&hist[dl], 1);
            if (pos < limit) ssrc[pos] = (int)(u32)p;
        }
    }
}

// ---------------------------------------------------------------------------
// W1,W2 (128x128, external dtype) -> bf16 transposed: Wt[c*128+k] = bf16(W[k][c])
__global__ __launch_bounds__(256) void prep_w(const void* __restrict__ W1,
                                              const void* __restrict__ W2,
                                              const int* __restrict__ flags,
                                              u16* __restrict__ W1t,
                                              u16* __restrict__ W2t) {
    int tid = blockIdx.x * 256 + threadIdx.x;
    if (tid < 2 * 128 * 128) {
        int which = tid >> 14;
        int r = tid & 16383;
        const void* W = which ? W2 : W1;
        u16* Wt = which ? W2t : W1t;
        int c = r >> 7, k = r & 127;
        Wt[c * 128 + k] = f2bs(ldext(W, flags[1], k * 128 + c));
    }
}

// ---------------------------------------------------------------------------
// MFMA GEMM: hs[v][c] = bf16( dinv[v] * sum_k X[v][k] * W[k][c] )
// mfma_f32_16x16x32_bf16. Block = 4 waves, 64 rows/block; wave = 16 rows x
// 128 cols = 8 col-tiles x 4 K-steps = 32 MFMAs. Wt staged in LDS, row
// stride 136 bf16 (2-way bank aliasing only -> free).
// Verified layouts (learn_hip m89/m91): A[m=lane&15][k=quad*8+j],
// B[n=lane&15][k=quad*8+j], C/D col=lane&15, row=quad*4+reg.
__global__ __launch_bounds__(256) void gemm_mfma(const void* __restrict__ Xv,
                                                 size_t xoff, int x_ext,
                                                 const u16* __restrict__ Wt,
                                                 const int* __restrict__ flags,
                                                 const float* __restrict__ dinv,
                                                 u16* __restrict__ hs, int n) {
    __shared__ u16 Ws[128 * 136];  // Wt[c][k], padded stride 136
    {
        u32* wsu = (u32*)Ws;
        const u32* wtu = (const u32*)Wt;
        for (int i = threadIdx.x; i < 128 * 64; i += 256) {
            int c = i >> 6, kk = i & 63;
            wsu[c * 68 + kk] = wtu[i];
        }
    }
    __syncthreads();

    const int wave = threadIdx.x >> 6;
    const int lane = threadIdx.x & 63;
    const int m = lane & 15;
    const int quad = lane >> 4;
    const int node0 = blockIdx.x * 64 + wave * 16;
    if (node0 >= n) return;

    const int xf32 = x_ext ? flags[1] : 0;   // internal buffers are bf16
    int va = node0 + m;
    if (va > n - 1) va = n - 1;              // clamp; stores guarded

    floatx4 acc[8];
#pragma unroll
    for (int t = 0; t < 8; ++t) acc[t] = (floatx4){0.f, 0.f, 0.f, 0.f};

#pragma unroll
    for (int ks = 0; ks < 4; ++ks) {
        bf16x8 a;
        if (xf32) {
            const float* Xf = (const float*)Xv + xoff + (size_t)va * 128 + ks * 32 + quad * 8;
            float4 x0 = *(const float4*)Xf;
            float4 x1 = *(const float4*)(Xf + 4);
            short8 as;
            as[0] = (short)f2bs(x0.x); as[1] = (short)f2bs(x0.y);
            as[2] = (short)f2bs(x0.z); as[3] = (short)f2bs(x0.w);
            as[4] = (short)f2bs(x1.x); as[5] = (short)f2bs(x1.y);
            as[6] = (short)f2bs(x1.z); as[7] = (short)f2bs(x1.w);
            a = __builtin_bit_cast(bf16x8, as);
        } else {
            const u16* Xb = (const u16*)Xv + xoff + (size_t)va * 128 + ks * 32 + quad * 8;
            a = *(const bf16x8*)Xb;
        }
#pragma unroll
        for (int t = 0; t < 8; ++t) {
            const bf16x8 b = *(const bf16x8*)(Ws + (16 * t + m) * 136 + ks * 32 + quad * 8);
            acc[t] = __builtin_amdgcn_mfma_f32_16x16x32_bf16(a, b, acc[t], 0, 0, 0);
        }
    }

#pragma unroll
    for (int r = 0; r < 4; ++r) {
        int v = node0 + quad * 4 + r;
        if (v < n) {
            float dv = dinv[v];
#pragma unroll
            for (int t = 0; t < 8; ++t)
                hs[(size_t)v * 128 + 16 * t + m] = f2bs(acc[t][r] * dv);
        }
    }
}

// ---------------------------------------------------------------------------
// out[v] = act( dinv[v] * (hs[v] + sum_{u in in(v)} hs[u]) + bias )
// hs: packed bf16 (lane reads u32 = 2 cols). Output: f32 (outf) or bf16 (outb).
// 8-deep unrolled edge loop: 8 independent row gathers in flight per wave.
// off/deg/dinv passed pre-offset by t*N (off values are global ssrc positions).
// If imp != null, also computes importance[v] = final[v] . Wc + bc (fused).
__global__ __launch_bounds__(256) void gather_kernel(const u16* __restrict__ hs,
                                                     const int* __restrict__ off,
                                                     const int* __restrict__ deg,
                                                     const int* __restrict__ ssrc,
                                                     const float* __restrict__ dinv,
                                                     const void* __restrict__ bias,
                                                     const int* __restrict__ flags,
                                                     float* __restrict__ outf,
                                                     u16* __restrict__ outb,
                                                     const void* __restrict__ Wc,
                                                     const void* __restrict__ bc,
                                                     float* __restrict__ imp,
                                                     int n, int relu) {
    int w = (blockIdx.x * 256 + threadIdx.x) >> 6;
    int lane = threadIdx.x & 63;
    if (w >= n) return;

    const u32* hsu = (const u32*)hs;         // row stride 64 u32
    u32 p = hsu[(size_t)w * 64 + lane];      // self-loop term
    float ax = lo2f(p), ay = hi2f(p);
    int i = __builtin_amdgcn_readfirstlane(off[w]);
    int end = i + __builtin_amdgcn_readfirstlane(deg[w]);
    unsigned nm1 = (unsigned)(n - 1);

    float bx = 0.f, by = 0.f, cx = 0.f, cy = 0.f, dx = 0.f, dy = 0.f;
    for (; i + 8 <= end; i += 8) {
        unsigned s0 = (unsigned)ssrc[i];     if (s0 > nm1) s0 = 0;
        unsigned s1 = (unsigned)ssrc[i + 1]; if (s1 > nm1) s1 = 0;
        unsigned s2 = (unsigned)ssrc[i + 2]; if (s2 > nm1) s2 = 0;
        unsigned s3 = (unsigned)ssrc[i + 3]; if (s3 > nm1) s3 = 0;
        unsigned s4 = (unsigned)ssrc[i + 4]; if (s4 > nm1) s4 = 0;
        unsigned s5 = (unsigned)ssrc[i + 5]; if (s5 > nm1) s5 = 0;
        unsigned s6 = (unsigned)ssrc[i + 6]; if (s6 > nm1) s6 = 0;
        unsigned s7 = (unsigned)ssrc[i + 7]; if (s7 > nm1) s7 = 0;
        u32 v0 = hsu[(size_t)s0 * 64 + lane];
        u32 v1 = hsu[(size_t)s1 * 64 + lane];
        u32 v2 = hsu[(size_t)s2 * 64 + lane];
        u32 v3 = hsu[(size_t)s3 * 64 + lane];
        u32 v4 = hsu[(size_t)s4 * 64 + lane];
        u32 v5 = hsu[(size_t)s5 * 64 + lane];
        u32 v6 = hsu[(size_t)s6 * 64 + lane];
        u32 v7 = hsu[(size_t)s7 * 64 + lane];
        ax += lo2f(v0); ay += hi2f(v0);
        bx += lo2f(v1); by += hi2f(v1);
        cx += lo2f(v2); cy += hi2f(v2);
        dx += lo2f(v3); dy += hi2f(v3);
        ax += lo2f(v4); ay += hi2f(v4);
        bx += lo2f(v5); by += hi2f(v5);
        cx += lo2f(v6); cy += hi2f(v6);
        dx += lo2f(v7); dy += hi2f(v7);
    }
    for (; i + 4 <= end; i += 4) {
        unsigned s0 = (unsigned)ssrc[i];     if (s0 > nm1) s0 = 0;
        unsigned s1 = (unsigned)ssrc[i + 1]; if (s1 > nm1) s1 = 0;
        unsigned s2 = (unsigned)ssrc[i + 2]; if (s2 > nm1) s2 = 0;
        unsigned s3 = (unsigned)ssrc[i + 3]; if (s3 > nm1) s3 = 0;
        u32 v0 = hsu[(size_t)s0 * 64 + lane];
        u32 v1 = hsu[(size_t)s1 * 64 + lane];
        u32 v2 = hsu[(size_t)s2 * 64 + lane];
        u32 v3 = hsu[(size_t)s3 * 64 + lane];
        ax += lo2f(v0); ay += hi2f(v0);
        bx += lo2f(v1); by += hi2f(v1);
        cx += lo2f(v2); cy += hi2f(v2);
        dx += lo2f(v3); dy += hi2f(v3);
    }
    for (; i < end; ++i) {
        unsigned s = (unsigned)ssrc[i];
        if (s > nm1) s = 0;
        u32 v = hsu[(size_t)s * 64 + lane];
        ax += lo2f(v);
        ay += hi2f(v);
    }
    ax += bx + cx + dx;
    ay += by + cy + dy;

    int ffl = flags[1];
    float dv = dinv[w];
    float o0 = dv * ax + ldext(bias, ffl, 2 * lane);
    float o1 = dv * ay + ldext(bias, ffl, 2 * lane + 1);
    if (relu) {
        o0 = fmaxf(o0, 0.f);
        o1 = fmaxf(o1, 0.f);
    }
    if (outf) ((float2*)outf)[(size_t)w * 64 + lane] = make_float2(o0, o1);
    else ((u32*)outb)[(size_t)w * 64 + lane] = (u32)f2bs(o0) | ((u32)f2bs(o1) << 16);

    if (imp) {   // fused importance: wave-reduce final[w] . Wc
        float cb = o0 * ldext(Wc, ffl, 2 * lane) + o1 * ldext(Wc, ffl, 2 * lane + 1);
        cb += __shfl_xor(cb, 32);
        cb += __shfl_xor(cb, 16);
        cb += __shfl_xor(cb, 8);
        cb += __shfl_xor(cb, 4);
        cb += __shfl_xor(cb, 2);
        cb += __shfl_xor(cb, 1);
        if (lane == 0) imp[w] = cb + ldext(bc, ffl, 0);
    }
}

// ---------------------------------------------------------------------------
extern "C" void kernel_launch(void* const* d_in, const int* in_sizes, int n_in,
                              void* d_out, int out_size, void* d_ws, size_t ws_size,
                              hipStream_t stream) {
    const int T = 2, C = 128;
    const int N = in_sizes[0] / (T * C);   // 50000
    const int S = in_sizes[1];             // edge buffer reported element count
    const int Emax = S / 4;                // upper bound on edges per timestep
    const int N2 = 2 * N;                  // global node space (both timesteps)

    const void* x_seq = d_in[0];
    const int* edges = (const int*)d_in[1];
    const void* W1 = d_in[2];
    const void* b1 = d_in[3];
    const void* W2 = d_in[4];
    const void* b2 = d_in[5];
    const void* Wc = d_in[6];
    const void* bc = d_in[7];

    // d_out is FLOAT32 (reference output dtype): [imp N][h_t0 N*C][h_t1 N*C]
    float* out = (float*)d_out;
    float* R0 = out + N;
    float* R1 = out + N + (size_t)N * C;

    // workspace (~33 MB); pairs aliases hsb+hmb (contiguous, dead during CSR build)
    char* p = (char*)d_ws;
    auto alloc = [&](size_t bytes) {
        char* r = p;
        p += (bytes + 255) & ~(size_t)255;
        return r;
    };
    int* flags = (int*)alloc(256);
    int* deg = (int*)alloc((size_t)N2 * 4);
    int* off = (int*)alloc((size_t)N2 * 4);
    float* dinv = (float*)alloc((size_t)N2 * 4);
    int* bkcnt = (int*)alloc(512 * 4);
    int* bkbase = (int*)alloc(512 * 4);
    int* ssrc = (int*)alloc((size_t)2 * Emax * 4);
    u16* W1t = (u16*)alloc(128 * 128 * 2);
    u16* W2t = (u16*)alloc(128 * 128 * 2);
    u16* hsb = (u16*)alloc((size_t)N * C * 2);   // bf16 scaled GEMM output
    u16* hmb = (u16*)alloc((size_t)N * C * 2);   // bf16 layer-1 activation
    u64* pairs = (u64*)hsb;                      // spans hsb+hmb (contiguous)

    // dst-range bucketing over 2N nodes: <=512 buckets, <=1024 LDS cursors
    int shift = 8;
    while ((((N2 + (1 << shift) - 1) >> shift) > 512) && shift < 10) ++shift;
    const int NBUK = (N2 + (1 << shift) - 1) >> shift;
    // fixed per-bucket pair capacity, sized to the hsb+hmb alias region
    // (~2x the expected per-bucket load for uniform edges)
    const size_t aliasBytes = (size_t)2 * N * C * 2;
    int capP = (int)(aliasBytes / (8 * (size_t)NBUK));

    const int gP = (2 * Emax + PCHUNK - 1) / PCHUNK;
    const int gN4 = (N + 3) / 4;            // wave-per-node kernels
    const int gG = (N + 63) / 64;           // mfma gemm: block per 64 nodes
    const int gW = (2 * 128 * 128 + 255) / 256;

    detect_kernel<<<1, 64, 0, stream>>>(edges, (const u32*)x_seq, flags, S, N);
    prep_w<<<gW, 256, 0, stream>>>(W1, W2, flags, W1t, W2t);

    // --- CSR build, both timesteps, no degree pre-pass ---
    hipMemsetAsync(bkcnt, 0, 512 * 4, stream);
    part_kernel<<<gP, 256, 0, stream>>>(edges, flags, bkcnt, pairs, N, shift, capP);
    scan_bk<<<1, 256, 0, stream>>>(bkcnt, bkbase, NBUK, capP);
    scat_kernel<<<NBUK, 256, 0, stream>>>(pairs, bkcnt, bkbase, deg, off, dinv,
                                          ssrc, N2, shift, capP);

    for (int t = 0; t < T; ++t) {
        float* Rt = (t == 0) ? R0 : R1;     // final output region for this t
        const int* off_t = off + (size_t)t * N;
        const int* deg_t = deg + (size_t)t * N;
        const float* dinv_t = dinv + (size_t)t * N;

        // --- layer 1: hsb = dinv*(X_t @ W1); hmb = relu(gather)+b1 (bf16) ---
        gemm_mfma<<<gG, 256, 0, stream>>>(x_seq, (size_t)t * N * C, 1, W1t, flags,
                                          dinv_t, hsb, N);
        gather_kernel<<<gN4, 256, 0, stream>>>(hsb, off_t, deg_t, ssrc, dinv_t, b1,
                                               flags, (float*)nullptr, hmb,
                                               nullptr, nullptr, (float*)nullptr,
                                               N, 1);

        // --- layer 2: hsb = dinv*(hmb @ W2); Rt = gather + b2 (f32) ---
        gemm_mfma<<<gG, 256, 0, stream>>>(hmb, 0, 0, W2t, flags, dinv_t, hsb, N);
        gather_kernel<<<gN4, 256, 0, stream>>>(hsb, off_t, deg_t, ssrc, dinv_t, b2,
                                               flags, Rt, (u16*)nullptr,
                                               Wc, bc, (t == 1) ? out : (float*)nullptr,
                                               N, 0);
    }
}

// Round 4
// 293.245 us; speedup vs baseline: 1.7737x; 1.1177x over previous
//
#include <hip/hip_runtime.h>
#include <hip/hip_bf16.h>

typedef unsigned int u32;
typedef unsigned short u16;
typedef unsigned long long u64;
typedef __bf16 bf16x8 __attribute__((ext_vector_type(8)));
typedef short short8 __attribute__((ext_vector_type(8)));
typedef float floatx4 __attribute__((ext_vector_type(4)));

__device__ inline float b2f(u16 b) { return __uint_as_float((u32)b << 16); }
__device__ inline float lo2f(u32 p) { return __uint_as_float(p << 16); }
__device__ inline float hi2f(u32 p) { return __uint_as_float(p & 0xffff0000u); }
__device__ inline u16 f2bs(float f) {   // RNE f32 -> bf16 bits
    __hip_bfloat16 h = __float2bfloat16(f);
    return *reinterpret_cast<u16*>(&h);
}
// element i of an external float array: f32 (fl=1) or packed bf16 (fl=0)
__device__ inline float ldext(const void* p, int fl, int i) {
    return fl ? ((const float*)p)[i] : b2f(((const u16*)p)[i]);
}

// ---------------------------------------------------------------------------
// flags[0]: edge stride (1 = int64 layout, 0 = int32)
// flags[1]: float inputs are f32 (1) or packed bf16 (0)
// flags[2]: E (edges per timestep), decided by probing data extent
__global__ __launch_bounds__(64) void detect_kernel(const int* __restrict__ eb,
                                                    const u32* __restrict__ xw,
                                                    int* __restrict__ flags,
                                                    int S, int n) {
    __shared__ int sh[64 * 3];
    int lane = threadIdx.x & 63;
    int zc = 0, explo = 0;
#pragma unroll
    for (int r = 0; r < 4; ++r) {
        int i = 64 * r + lane;
        zc += (eb[2 * i + 1] == 0) ? 1 : 0;   // int64: odd dwords are hi-words = 0
        u32 w = xw[i];
        int e = (int)((w >> 7) & 0xFF);       // exponent field of LOW half as bf16
        explo += (e >= 96 && e <= 140) ? 1 : 0;
    }
    sh[lane] = zc;
    sh[64 + lane] = explo;
    __syncthreads();
    int fl = 0;
    {
        int z = 0;
        for (int j = 0; j < 64; ++j) z += sh[j];
        fl = (z > 200) ? 1 : 0;   // wave-uniform
    }
    // probe logical indices [S/2, S/2+256): valid node ids => S counts logical
    // elements (E = S/4); garbage => S counts int32 words (E = S/8).
    int vc = 0;
#pragma unroll
    for (int r = 0; r < 4; ++r) {
        int li = S / 2 + 64 * r + lane;
        int v = fl ? eb[2 * li] : eb[li];
        vc += ((unsigned)v < (unsigned)n) ? 1 : 0;
    }
    sh[128 + lane] = vc;
    __syncthreads();
    if (lane == 0) {
        int vtot = 0, etot = 0;
        for (int j = 0; j < 64; ++j) vtot += sh[128 + j];
        for (int j = 0; j < 64; ++j) etot += sh[64 + j];
        flags[0] = fl;
        flags[1] = (etot >= 192) ? 0 : 1;   // bf16-packed signature else f32
        flags[2] = (vtot >= 240) ? (S / 4) : (S / 8);
    }
}

__device__ inline int load_edge(const int* eb, int fl, int idx) {
    return eb[fl ? (idx << 1) : idx];
}

// ---------------------------------------------------------------------------
// CSR build pass 1 (both timesteps): partition edges into global-dst-range
// buckets at FIXED capacity capP (region b*capP, no scan needed). Per-block
// LDS histogram -> one global atomicAdd per bucket -> (g_dst, g_src) u64
// pairs in ~150 B contiguous runs (near-full cache lines). Src stored as
// GLOBAL id t*N+src so downstream gathers index the unified 2N-row buffers.
#define PCHUNK 4096
__global__ __launch_bounds__(256) void part_kernel(const int* __restrict__ eb,
                                                   const int* __restrict__ flags,
                                                   int* __restrict__ bkcnt,
                                                   u64* __restrict__ pairs,
                                                   int n, int shift, int capP) {
    __shared__ int cnt[512];
    __shared__ int gbase[512];
    const int E = flags[2];
    const int fl = flags[0];
    const int nbuk = (2 * n + (1 << shift) - 1) >> shift;
    const int tid = threadIdx.x;
    for (int i = tid; i < nbuk; i += 256) cnt[i] = 0;
    __syncthreads();
    const int e0 = blockIdx.x * PCHUNK;
    u32 sv[16]; int gv[16], rk[16];
#pragma unroll
    for (int j = 0; j < 16; ++j) {
        int e = e0 + j * 256 + tid;
        u32 gs = 0; int g = -1;
        if (e < 2 * E) {
            int t = (e >= E) ? 1 : 0;
            int le = e - t * E;
            gs = (u32)(t * n) + (u32)load_edge(eb, fl, t * 2 * E + le);
            unsigned du = (unsigned)load_edge(eb, fl, t * 2 * E + E + le);
            if (du < (unsigned)n) g = t * n + (int)du;
        }
        sv[j] = gs;
        gv[j] = g;
        rk[j] = (g >= 0) ? atomicAdd(&cnt[g >> shift], 1) : 0;   // rank in bucket
    }
    __syncthreads();
    for (int b = tid; b < nbuk; b += 256) {
        int c = cnt[b];
        gbase[b] = c ? atomicAdd(&bkcnt[b], c) : 0;              // reserve run
    }
    __syncthreads();
#pragma unroll
    for (int j = 0; j < 16; ++j) {
        if (gv[j] >= 0) {
            int b = gv[j] >> shift;
            int idx = gbase[b] + rk[j];
            if (idx < capP)                                      // overflow guard
                pairs[(size_t)b * capP + idx] =
                    ((u64)(u32)gv[j] << 32) | sv[j];
        }
    }
}

// ---------------------------------------------------------------------------
// CSR build pass 2: one block per bucket. LDS histogram of the bucket's pairs
// gives local degrees; LDS exclusive scan gives local CSR offsets into the
// SPARSE ssrc layout (bucket region b*capP); deg/off/dinv written coalesced;
// then in-bucket ssrc scatter (~16 KB window, L2-hot, full-line writebacks).
__global__ __launch_bounds__(256) void scat_kernel(const u64* __restrict__ pairs,
                                                   const int* __restrict__ bkcnt,
                                                   int* __restrict__ deg,
                                                   int* __restrict__ off,
                                                   float* __restrict__ dinv,
                                                   int* __restrict__ ssrc,
                                                   int n2, int shift, int capP) {
    __shared__ int hist[1024];   // histogram, then reused as scatter cursors
    __shared__ int lscan[256];
    const int b = blockIdx.x;
    const int d0 = b << shift;
    if (d0 >= n2) return;
    int nn = (1 << shift);
    if (d0 + nn > n2) nn = n2 - d0;
    const int tid = threadIdx.x;
    for (int j = tid; j < nn; j += 256) hist[j] = 0;
    __syncthreads();
    int cnt = bkcnt[b];
    if (cnt > capP) cnt = capP;
    const int gb = b * capP;                 // fixed sparse base for this bucket
    const u64* pb = pairs + (size_t)gb;
    for (int i = tid; i < cnt; i += 256) {
        unsigned dl = (unsigned)(int)(pb[i] >> 32) - (unsigned)d0;
        if (dl < (unsigned)nn) atomicAdd(&hist[dl], 1);
    }
    __syncthreads();
    // exclusive scan of hist[0..nn): thread t owns elements [4t, 4t+4)
    int base4 = tid * 4;
    int s0 = 0, s1 = 0, s2 = 0, s3 = 0;
    if (base4 < nn) {
        s0 = hist[base4];
        s1 = (base4 + 1 < nn) ? hist[base4 + 1] : 0;
        s2 = (base4 + 2 < nn) ? hist[base4 + 2] : 0;
        s3 = (base4 + 3 < nn) ? hist[base4 + 3] : 0;
    }
    int tsum = s0 + s1 + s2 + s3;
    lscan[tid] = tsum;
    __syncthreads();
    int val = tsum;
    for (int o = 1; o < 256; o <<= 1) {
        int add = (tid >= o) ? lscan[tid - o] : 0;
        __syncthreads();
        val += add;
        lscan[tid] = val;
        __syncthreads();
    }
    int texcl = val - tsum;                  // exclusive prefix of this thread's 4
    if (base4 < nn) {
        int g = d0 + base4;
        int o0 = gb + texcl;
        deg[g] = s0; off[g] = o0; dinv[g] = rsqrtf((float)(s0 + 1));
        hist[base4] = o0;
        if (base4 + 1 < nn) {
            int o1 = o0 + s0;
            deg[g + 1] = s1; off[g + 1] = o1; dinv[g + 1] = rsqrtf((float)(s1 + 1));
            hist[base4 + 1] = o1;
        }
        if (base4 + 2 < nn) {
            int o2 = o0 + s0 + s1;
            deg[g + 2] = s2; off[g + 2] = o2; dinv[g + 2] = rsqrtf((float)(s2 + 1));
            hist[base4 + 2] = o2;
        }
        if (base4 + 3 < nn) {
            int o3 = o0 + s0 + s1 + s2;
            deg[g + 3] = s3; off[g + 3] = o3; dinv[g + 3] = rsqrtf((float)(s3 + 1));
            hist[base4 + 3] = o3;
        }
    }
    __syncthreads();
    const int limit = gb + cnt;
    for (int i = tid; i < cnt; i += 256) {
        u64 p = pb[i];
        unsigned dl = (unsigned)(int)(p >> 32) - (unsigned)d0;
        if (dl < (unsigned)nn) {
            int pos = atomicAdd(&hist[dl], 1);
            if (pos < limit) ssrc[pos] = (int)(u32)p;
        }
    }
}

// ---------------------------------------------------------------------------
// W1,W2 (128x128, external dtype) -> bf16 transposed: Wt[c*128+k] = bf16(W[k][c])
__global__ __launch_bounds__(256) void prep_w(const void* __restrict__ W1,
                                              const void* __restrict__ W2,
                                              const int* __restrict__ flags,
                                              u16* __restrict__ W1t,
                                              u16* __restrict__ W2t) {
    int tid = blockIdx.x * 256 + threadIdx.x;
    if (tid < 2 * 128 * 128) {
        int which = tid >> 14;
        int r = tid & 16383;
        const void* W = which ? W2 : W1;
        u16* Wt = which ? W2t : W1t;
        int c = r >> 7, k = r & 127;
        Wt[c * 128 + k] = f2bs(ldext(W, flags[1], k * 128 + c));
    }
}

// ---------------------------------------------------------------------------
// MFMA GEMM over the unified 2N-row space: hs[g][c] = bf16( dinv[g] * X[g].W )
// mfma_f32_16x16x32_bf16. Block = 4 waves, 64 rows/block; wave = 16 rows x
// 128 cols = 8 col-tiles x 4 K-steps = 32 MFMAs. Wt staged in LDS, row
// stride 136 bf16 (2-way bank aliasing only -> free).
// Verified layouts (learn_hip m89/m91): A[m=lane&15][k=quad*8+j],
// B[n=lane&15][k=quad*8+j], C/D col=lane&15, row=quad*4+reg.
__global__ __launch_bounds__(256) void gemm_mfma(const void* __restrict__ Xv,
                                                 int x_ext,
                                                 const u16* __restrict__ Wt,
                                                 const int* __restrict__ flags,
                                                 const float* __restrict__ dinv,
                                                 u16* __restrict__ hs, int n) {
    __shared__ u16 Ws[128 * 136];  // Wt[c][k], padded stride 136
    {
        u32* wsu = (u32*)Ws;
        const u32* wtu = (const u32*)Wt;
        for (int i = threadIdx.x; i < 128 * 64; i += 256) {
            int c = i >> 6, kk = i & 63;
            wsu[c * 68 + kk] = wtu[i];
        }
    }
    __syncthreads();

    const int wave = threadIdx.x >> 6;
    const int lane = threadIdx.x & 63;
    const int m = lane & 15;
    const int quad = lane >> 4;
    const int node0 = blockIdx.x * 64 + wave * 16;
    if (node0 >= n) return;

    const int xf32 = x_ext ? flags[1] : 0;   // internal buffers are bf16
    int va = node0 + m;
    if (va > n - 1) va = n - 1;              // clamp; stores guarded

    floatx4 acc[8];
#pragma unroll
    for (int t = 0; t < 8; ++t) acc[t] = (floatx4){0.f, 0.f, 0.f, 0.f};

#pragma unroll
    for (int ks = 0; ks < 4; ++ks) {
        bf16x8 a;
        if (xf32) {
            const float* Xf = (const float*)Xv + (size_t)va * 128 + ks * 32 + quad * 8;
            float4 x0 = *(const float4*)Xf;
            float4 x1 = *(const float4*)(Xf + 4);
            short8 as;
            as[0] = (short)f2bs(x0.x); as[1] = (short)f2bs(x0.y);
            as[2] = (short)f2bs(x0.z); as[3] = (short)f2bs(x0.w);
            as[4] = (short)f2bs(x1.x); as[5] = (short)f2bs(x1.y);
            as[6] = (short)f2bs(x1.z); as[7] = (short)f2bs(x1.w);
            a = __builtin_bit_cast(bf16x8, as);
        } else {
            const u16* Xb = (const u16*)Xv + (size_t)va * 128 + ks * 32 + quad * 8;
            a = *(const bf16x8*)Xb;
        }
#pragma unroll
        for (int t = 0; t < 8; ++t) {
            const bf16x8 b = *(const bf16x8*)(Ws + (16 * t + m) * 136 + ks * 32 + quad * 8);
            acc[t] = __builtin_amdgcn_mfma_f32_16x16x32_bf16(a, b, acc[t], 0, 0, 0);
        }
    }

#pragma unroll
    for (int r = 0; r < 4; ++r) {
        int v = node0 + quad * 4 + r;
        if (v < n) {
            float dv = dinv[v];
#pragma unroll
            for (int t = 0; t < 8; ++t)
                hs[(size_t)v * 128 + 16 * t + m] = f2bs(acc[t][r] * dv);
        }
    }
}

// ---------------------------------------------------------------------------
// out[g] = act( dinv[g] * (hs[g] + sum_{u in in(g)} hs[u]) + bias ), g in [0,2N)
// hs: packed bf16, 2N rows (lane reads u32 = 2 cols). ssrc holds GLOBAL ids.
// Output: f32 (outf, g-indexed = R0||R1) or bf16 (outb). 8-deep unrolled edge
// loop: 8 independent row gathers in flight per wave. If imp != null, rows
// g >= half additionally wave-reduce importance[g-half] = final . Wc + bc.
__global__ __launch_bounds__(256) void gather_kernel(const u16* __restrict__ hs,
                                                     const int* __restrict__ off,
                                                     const int* __restrict__ deg,
                                                     const int* __restrict__ ssrc,
                                                     const float* __restrict__ dinv,
                                                     const void* __restrict__ bias,
                                                     const int* __restrict__ flags,
                                                     float* __restrict__ outf,
                                                     u16* __restrict__ outb,
                                                     const void* __restrict__ Wc,
                                                     const void* __restrict__ bc,
                                                     float* __restrict__ imp,
                                                     int n2, int half, int relu) {
    int w = (blockIdx.x * 256 + threadIdx.x) >> 6;
    int lane = threadIdx.x & 63;
    if (w >= n2) return;

    const u32* hsu = (const u32*)hs;         // row stride 64 u32
    u32 p = hsu[(size_t)w * 64 + lane];      // self-loop term
    float ax = lo2f(p), ay = hi2f(p);
    int i = __builtin_amdgcn_readfirstlane(off[w]);
    int end = i + __builtin_amdgcn_readfirstlane(deg[w]);
    unsigned nm1 = (unsigned)(n2 - 1);

    float bx = 0.f, by = 0.f, cx = 0.f, cy = 0.f, dx = 0.f, dy = 0.f;
    for (; i + 8 <= end; i += 8) {
        unsigned s0 = (unsigned)ssrc[i];     if (s0 > nm1) s0 = 0;
        unsigned s1 = (unsigned)ssrc[i + 1]; if (s1 > nm1) s1 = 0;
        unsigned s2 = (unsigned)ssrc[i + 2]; if (s2 > nm1) s2 = 0;
        unsigned s3 = (unsigned)ssrc[i + 3]; if (s3 > nm1) s3 = 0;
        unsigned s4 = (unsigned)ssrc[i + 4]; if (s4 > nm1) s4 = 0;
        unsigned s5 = (unsigned)ssrc[i + 5]; if (s5 > nm1) s5 = 0;
        unsigned s6 = (unsigned)ssrc[i + 6]; if (s6 > nm1) s6 = 0;
        unsigned s7 = (unsigned)ssrc[i + 7]; if (s7 > nm1) s7 = 0;
        u32 v0 = hsu[(size_t)s0 * 64 + lane];
        u32 v1 = hsu[(size_t)s1 * 64 + lane];
        u32 v2 = hsu[(size_t)s2 * 64 + lane];
        u32 v3 = hsu[(size_t)s3 * 64 + lane];
        u32 v4 = hsu[(size_t)s4 * 64 + lane];
        u32 v5 = hsu[(size_t)s5 * 64 + lane];
        u32 v6 = hsu[(size_t)s6 * 64 + lane];
        u32 v7 = hsu[(size_t)s7 * 64 + lane];
        ax += lo2f(v0); ay += hi2f(v0);
        bx += lo2f(v1); by += hi2f(v1);
        cx += lo2f(v2); cy += hi2f(v2);
        dx += lo2f(v3); dy += hi2f(v3);
        ax += lo2f(v4); ay += hi2f(v4);
        bx += lo2f(v5); by += hi2f(v5);
        cx += lo2f(v6); cy += hi2f(v6);
        dx += lo2f(v7); dy += hi2f(v7);
    }
    for (; i + 4 <= end; i += 4) {
        unsigned s0 = (unsigned)ssrc[i];     if (s0 > nm1) s0 = 0;
        unsigned s1 = (unsigned)ssrc[i + 1]; if (s1 > nm1) s1 = 0;
        unsigned s2 = (unsigned)ssrc[i + 2]; if (s2 > nm1) s2 = 0;
        unsigned s3 = (unsigned)ssrc[i + 3]; if (s3 > nm1) s3 = 0;
        u32 v0 = hsu[(size_t)s0 * 64 + lane];
        u32 v1 = hsu[(size_t)s1 * 64 + lane];
        u32 v2 = hsu[(size_t)s2 * 64 + lane];
        u32 v3 = hsu[(size_t)s3 * 64 + lane];
        ax += lo2f(v0); ay += hi2f(v0);
        bx += lo2f(v1); by += hi2f(v1);
        cx += lo2f(v2); cy += hi2f(v2);
        dx += lo2f(v3); dy += hi2f(v3);
    }
    for (; i < end; ++i) {
        unsigned s = (unsigned)ssrc[i];
        if (s > nm1) s = 0;
        u32 v = hsu[(size_t)s * 64 + lane];
        ax += lo2f(v);
        ay += hi2f(v);
    }
    ax += bx + cx + dx;
    ay += by + cy + dy;

    int ffl = flags[1];
    float dv = dinv[w];
    float o0 = dv * ax + ldext(bias, ffl, 2 * lane);
    float o1 = dv * ay + ldext(bias, ffl, 2 * lane + 1);
    if (relu) {
        o0 = fmaxf(o0, 0.f);
        o1 = fmaxf(o1, 0.f);
    }
    if (outf) ((float2*)outf)[(size_t)w * 64 + lane] = make_float2(o0, o1);
    else ((u32*)outb)[(size_t)w * 64 + lane] = (u32)f2bs(o0) | ((u32)f2bs(o1) << 16);

    if (imp && w >= half) {   // fused importance on final-timestep rows
        float cb = o0 * ldext(Wc, ffl, 2 * lane) + o1 * ldext(Wc, ffl, 2 * lane + 1);
        cb += __shfl_xor(cb, 32);
        cb += __shfl_xor(cb, 16);
        cb += __shfl_xor(cb, 8);
        cb += __shfl_xor(cb, 4);
        cb += __shfl_xor(cb, 2);
        cb += __shfl_xor(cb, 1);
        if (lane == 0) imp[w - half] = cb + ldext(bc, ffl, 0);
    }
}

// ---------------------------------------------------------------------------
extern "C" void kernel_launch(void* const* d_in, const int* in_sizes, int n_in,
                              void* d_out, int out_size, void* d_ws, size_t ws_size,
                              hipStream_t stream) {
    const int T = 2, C = 128;
    const int N = in_sizes[0] / (T * C);   // 50000
    const int S = in_sizes[1];             // edge buffer reported element count
    const int Emax = S / 4;                // upper bound on edges per timestep
    const int N2 = 2 * N;                  // global node space (both timesteps)
    (void)Emax;

    const void* x_seq = d_in[0];
    const int* edges = (const int*)d_in[1];
    const void* W1 = d_in[2];
    const void* b1 = d_in[3];
    const void* W2 = d_in[4];
    const void* b2 = d_in[5];
    const void* Wc = d_in[6];
    const void* bc = d_in[7];

    // d_out is FLOAT32 (reference output dtype): [imp N][h_t0 N*C][h_t1 N*C]
    // R0||R1 is contiguous and g-indexed: row g of the fused layer-2 output.
    float* out = (float*)d_out;
    float* R = out + N;

    // workspace (~78 MB of 256 MB); pairs aliases hsb+hmb (contiguous, dead
    // during CSR build — first GEMM write happens after scat in stream order)
    char* p = (char*)d_ws;
    auto alloc = [&](size_t bytes) {
        char* r = p;
        p += (bytes + 255) & ~(size_t)255;
        return r;
    };
    int* flags = (int*)alloc(256);
    int* deg = (int*)alloc((size_t)N2 * 4);
    int* off = (int*)alloc((size_t)N2 * 4);
    float* dinv = (float*)alloc((size_t)N2 * 4);
    int* bkcnt = (int*)alloc(512 * 4);

    // dst-range bucketing over 2N nodes: <=512 buckets, <=1024 LDS cursors
    int shift = 8;
    while ((((N2 + (1 << shift) - 1) >> shift) > 512) && shift < 10) ++shift;
    const int NBUK = (N2 + (1 << shift) - 1) >> shift;
    // fixed per-bucket pair capacity, sized to the hsb+hmb alias region
    // (~4x the expected per-bucket load for uniform edges)
    const size_t aliasBytes = (size_t)2 * N2 * C * 2;
    const int capP = (int)(aliasBytes / (8 * (size_t)NBUK));

    int* ssrc = (int*)alloc((size_t)NBUK * capP * 4);   // sparse CSR payload
    u16* W1t = (u16*)alloc(128 * 128 * 2);
    u16* W2t = (u16*)alloc(128 * 128 * 2);
    u16* hsb = (u16*)alloc((size_t)N2 * C * 2);  // bf16 scaled GEMM output (2N rows)
    u16* hmb = (u16*)alloc((size_t)N2 * C * 2);  // bf16 layer-1 activation (2N rows)
    u64* pairs = (u64*)hsb;                      // spans hsb+hmb (contiguous)

    const int gP = (2 * Emax + PCHUNK - 1) / PCHUNK;
    const int gN2 = (N2 + 3) / 4;           // wave-per-node kernels (2N nodes)
    const int gG2 = (N2 + 63) / 64;         // mfma gemm: block per 64 rows
    const int gW = (2 * 128 * 128 + 255) / 256;

    detect_kernel<<<1, 64, 0, stream>>>(edges, (const u32*)x_seq, flags, S, N);
    prep_w<<<gW, 256, 0, stream>>>(W1, W2, flags, W1t, W2t);

    // --- CSR build, both timesteps, fixed bucket bases (no scan) ---
    hipMemsetAsync(bkcnt, 0, 512 * 4, stream);
    part_kernel<<<gP, 256, 0, stream>>>(edges, flags, bkcnt, pairs, N, shift, capP);
    scat_kernel<<<NBUK, 256, 0, stream>>>(pairs, bkcnt, deg, off, dinv,
                                          ssrc, N2, shift, capP);

    // --- layer 1 over all 2N rows: hsb = dinv*(X @ W1); hmb = relu(gather)+b1 ---
    gemm_mfma<<<gG2, 256, 0, stream>>>(x_seq, 1, W1t, flags, dinv, hsb, N2);
    gather_kernel<<<gN2, 256, 0, stream>>>(hsb, off, deg, ssrc, dinv, b1, flags,
                                           (float*)nullptr, hmb,
                                           nullptr, nullptr, (float*)nullptr,
                                           N2, N, 1);

    // --- layer 2 over all 2N rows: hsb = dinv*(hmb @ W2); R = gather + b2 ---
    gemm_mfma<<<gG2, 256, 0, stream>>>(hmb, 0, W2t, flags, dinv, hsb, N2);
    gather_kernel<<<gN2, 256, 0, stream>>>(hsb, off, deg, ssrc, dinv, b2, flags,
                                           R, (u16*)nullptr,
                                           Wc, bc, out,
                                           N2, N, 0);
}